// Round 3
// baseline (615.001 us; speedup 1.0000x reference)
//
#include <hip/hip_runtime.h>
#include <hip/hip_bf16.h>
#include <cstdint>
#include <cstddef>

// ---------------------------------------------------------------------------
// SelfAttentionV1: out = softmax((x Wq^T)(x Wk^T)^T / 32) (x Wv^T)
// N=8192, D=1024. Round 3: ring-4 pipeline deepened to prefetch distance 3
// (vmcnt(8) steady-state) -- covers HBM-miss latency (~900cy) with ~940cy of
// in-flight compute. Otherwise identical to round 2 (clean A/B on depth).
// ---------------------------------------------------------------------------

typedef __attribute__((ext_vector_type(8))) short short8;     // bf16x8 MFMA frag
typedef __attribute__((ext_vector_type(8))) unsigned short ushort8;
typedef __attribute__((ext_vector_type(4))) float f32x4;

#define FENCE asm volatile("" ::: "memory")

__device__ __forceinline__ unsigned short f2bf(float f) {
  unsigned u = __float_as_uint(f);
  u += 0x7fffu + ((u >> 16) & 1u);      // round-to-nearest-even
  return (unsigned short)(u >> 16);
}
__device__ __forceinline__ float bf2f(unsigned short h) {
  return __uint_as_float(((unsigned)h) << 16);
}

// async global->LDS, 16 bytes per lane (wave-uniform LDS base + lane*16)
__device__ __forceinline__ void glds16(const void* g, void* l) {
  __builtin_amdgcn_global_load_lds((__attribute__((address_space(1))) void*)g,
                                   (__attribute__((address_space(3))) void*)l,
                                   16, 0, 0);
}

// ---- fp32 -> bf16 cast, 8 elems/thread ----
__global__ __launch_bounds__(256) void cast_kernel(const float* __restrict__ in,
                                                   unsigned short* __restrict__ out,
                                                   int n8) {
  int i = blockIdx.x * 256 + threadIdx.x;
  if (i >= n8) return;
  const f32x4* in4 = (const f32x4*)in;
  f32x4 a = in4[2 * i];
  f32x4 b = in4[2 * i + 1];
  ushort8 o;
#pragma unroll
  for (int j = 0; j < 4; ++j) o[j] = f2bf(a[j]);
#pragma unroll
  for (int j = 0; j < 4; ++j) o[4 + j] = f2bf(b[j]);
  ((ushort8*)out)[i] = o;
}

// ---------------------------------------------------------------------------
// GEMM core: C[gm0..+256, gn0..+256] = scale * A * B^T  (A,B bf16 [*, K] rows)
// 512 thr = 8 waves (2M x 4N), wave-out 128x64 (8x4 frags of 16x16x32).
// BK=32, RING=4 LDS slots (128 KiB), prefetch distance 3, vmcnt(8) boundary
// (tiles t+2,t+3 in flight = 8 loads/wave). Requires NT >= 3.
// LDS plane [256 rows][32 cols] bf16 (64B rows), swizzle: colbyte ^=
// ((row>>1)&3)<<4; staging pre-swizzles the GLOBAL source (rule #21).
// ---------------------------------------------------------------------------
#define MFMA_OP(mi, ni, av, bv) \
  acc[mi][ni] = __builtin_amdgcn_mfma_f32_16x16x32_bf16(av, bv, acc[mi][ni], 0, 0, 0)

template <typename OutT>
__device__ __forceinline__ void gemm_core(
    const unsigned short* __restrict__ A, const unsigned short* __restrict__ B,
    OutT* __restrict__ C, int ldc, size_t ldab /*row bytes*/, int NT,
    int gm0, int gn0, float scale, char* lA, char* lB) {
  const int tid = threadIdx.x;
  const int lane = tid & 63, w = tid >> 6;
  const int wm = w >> 2, wn = w & 3;            // 2M x 4N wave grid

  // ---- staging (writer) per-lane constants ----
  const int rc0 = w * 32 + (lane >> 2);
  const int rc1 = rc0 + 16;
  const int scol = ((lane & 3) << 4) ^ (((lane >> 3) & 3) << 4);
  const char* pA0 = (const char*)A + (size_t)(gm0 + rc0) * ldab + scol;
  const char* pA1 = (const char*)A + (size_t)(gm0 + rc1) * ldab + scol;
  const char* pB0 = (const char*)B + (size_t)(gn0 + rc0) * ldab + scol;
  const char* pB1 = (const char*)B + (size_t)(gn0 + rc1) * ldab + scol;
  char* dA = lA + w * 2048;   // + slot*16384 (+1024 for c=1)
  char* dB = lB + w * 2048;

  // ---- reader per-lane constants ----
  const int colb = ((lane >> 4) << 4) ^ (((lane >> 1) & 3) << 4);
  const int aoff = (wm * 128 + (lane & 15)) * 64 + colb;
  const int boff = (wn * 64 + (lane & 15)) * 64 + colb;

  f32x4 acc[8][4];
#pragma unroll
  for (int m = 0; m < 8; ++m)
#pragma unroll
    for (int n = 0; n < 4; ++n) acc[m][n] = (f32x4)(0.0f);

  // ---- prologue: stage tiles 0,1,2; vmcnt(8) => tile 0 landed (all waves
  // then barrier => globally visible).
  for (int t = 0; t < 3; ++t) {
    glds16(pA0 + (size_t)t * 64, dA + t * 16384);
    glds16(pA1 + (size_t)t * 64, dA + t * 16384 + 1024);
    glds16(pB0 + (size_t)t * 64, dB + t * 16384);
    glds16(pB1 + (size_t)t * 64, dB + t * 16384 + 1024);
  }
  asm volatile("s_waitcnt vmcnt(8)" ::: "memory");
  __builtin_amdgcn_s_barrier();
  FENCE;

  for (int t = 0; t < NT; ++t) {
    const int slot = t & 3;
    const char* As = lA + slot * 16384;
    const char* Bs = lB + slot * 16384;
    const bool stg = (t + 3 < NT);
    const int s3 = (t + 3) & 3;       // slot of t-1: reads done at t-1's barrier
    const size_t go = (size_t)(t + 3) * 64;
    short8 a0, a1, a2, a3, b0, b1, b2, b3;

    // ---- phase 0: stage A.c0(t+3) | read A[mi0-3], B[ni0-1] | 8 MFMA
    if (stg) glds16(pA0 + go, dA + s3 * 16384);
    a0 = *(const short8*)(As + aoff);
    a1 = *(const short8*)(As + aoff + 1024);
    a2 = *(const short8*)(As + aoff + 2048);
    a3 = *(const short8*)(As + aoff + 3072);
    b0 = *(const short8*)(Bs + boff);
    b1 = *(const short8*)(Bs + boff + 1024);
    __builtin_amdgcn_s_setprio(1);
    MFMA_OP(0, 0, a0, b0); MFMA_OP(0, 1, a0, b1);
    MFMA_OP(1, 0, a1, b0); MFMA_OP(1, 1, a1, b1);
    MFMA_OP(2, 0, a2, b0); MFMA_OP(2, 1, a2, b1);
    MFMA_OP(3, 0, a3, b0); MFMA_OP(3, 1, a3, b1);
    __builtin_amdgcn_s_setprio(0);
    FENCE; __builtin_amdgcn_s_barrier(); FENCE;

    // ---- phase 1: stage A.c1 | read B[ni2-3] | 8 MFMA
    if (stg) glds16(pA1 + go, dA + s3 * 16384 + 1024);
    b2 = *(const short8*)(Bs + boff + 2048);
    b3 = *(const short8*)(Bs + boff + 3072);
    __builtin_amdgcn_s_setprio(1);
    MFMA_OP(0, 2, a0, b2); MFMA_OP(0, 3, a0, b3);
    MFMA_OP(1, 2, a1, b2); MFMA_OP(1, 3, a1, b3);
    MFMA_OP(2, 2, a2, b2); MFMA_OP(2, 3, a2, b3);
    MFMA_OP(3, 2, a3, b2); MFMA_OP(3, 3, a3, b3);
    __builtin_amdgcn_s_setprio(0);
    FENCE; __builtin_amdgcn_s_barrier(); FENCE;

    // ---- phase 2: stage B.c0 | read A[mi4-7] | 8 MFMA
    if (stg) glds16(pB0 + go, dB + s3 * 16384);
    a0 = *(const short8*)(As + aoff + 4096);
    a1 = *(const short8*)(As + aoff + 5120);
    a2 = *(const short8*)(As + aoff + 6144);
    a3 = *(const short8*)(As + aoff + 7168);
    __builtin_amdgcn_s_setprio(1);
    MFMA_OP(4, 0, a0, b0); MFMA_OP(4, 1, a0, b1);
    MFMA_OP(5, 0, a1, b0); MFMA_OP(5, 1, a1, b1);
    MFMA_OP(6, 0, a2, b0); MFMA_OP(6, 1, a2, b1);
    MFMA_OP(7, 0, a3, b0); MFMA_OP(7, 1, a3, b1);
    __builtin_amdgcn_s_setprio(0);
    FENCE; __builtin_amdgcn_s_barrier(); FENCE;

    // ---- phase 3: stage B.c1 | 8 MFMA | counted wait | barrier
    if (stg) glds16(pB1 + go, dB + s3 * 16384 + 1024);
    __builtin_amdgcn_s_setprio(1);
    MFMA_OP(4, 2, a0, b2); MFMA_OP(4, 3, a0, b3);
    MFMA_OP(5, 2, a1, b2); MFMA_OP(5, 3, a1, b3);
    MFMA_OP(6, 2, a2, b2); MFMA_OP(6, 3, a2, b3);
    MFMA_OP(7, 2, a3, b2); MFMA_OP(7, 3, a3, b3);
    __builtin_amdgcn_s_setprio(0);
    // ensure tile t+1 fully landed; keep tiles t+2,t+3 in flight
    if (t + 3 < NT)      asm volatile("s_waitcnt vmcnt(8)" ::: "memory");
    else if (t + 2 < NT) asm volatile("s_waitcnt vmcnt(4)" ::: "memory");
    else                 asm volatile("s_waitcnt vmcnt(0)" ::: "memory");
    __builtin_amdgcn_s_barrier();
    FENCE;
  }

  // ---- epilogue: C row=(lane>>4)*4+j, col=lane&15 (m89-verified layout)
  const int r0 = gm0 + wm * 128 + ((lane >> 4) << 2);
  const int c0 = gn0 + wn * 64 + (lane & 15);
#pragma unroll
  for (int mi = 0; mi < 8; ++mi) {
#pragma unroll
    for (int ni = 0; ni < 4; ++ni) {
      f32x4 v = acc[mi][ni];
#pragma unroll
      for (int j = 0; j < 4; ++j) {
        float val = v[j] * scale;
        size_t idx = (size_t)(r0 + mi * 16 + j) * ldc + (c0 + ni * 16);
        if (sizeof(OutT) == 2) ((unsigned short*)C)[idx] = f2bf(val);
        else                   ((float*)C)[idx] = val;
      }
    }
  }
}

// bijective XCD chunking: consecutive logical blocks land on the same XCD
__device__ __forceinline__ void swz_block(int& bx, int& by, int& bz) {
  const int gx = gridDim.x, gy = gridDim.y;
  const int f = (blockIdx.z * gy + blockIdx.y) * gx + blockIdx.x;
  const int nwg = gx * gy * gridDim.z;      // all grids are multiples of 8
  const int q = nwg >> 3;
  const int l = (f & 7) * q + (f >> 3);
  bx = l % gx;
  const int r = l / gx;
  by = r % gy;
  bz = r / gy;
}

__global__ __launch_bounds__(512, 2) void gemm_s_kernel(
    const unsigned short* __restrict__ Q, const unsigned short* __restrict__ Kh,
    unsigned short* __restrict__ S) {
  __shared__ char lA[4 * 16384];
  __shared__ char lB[4 * 16384];
  int bx, by, bz; swz_block(bx, by, bz);
  gemm_core<unsigned short>(Q, Kh, S, 8192, 2048, 32, by * 256, bx * 256,
                            0.03125f, lA, lB);
}

__global__ __launch_bounds__(512, 2) void gemm_qkv_kernel(
    const unsigned short* __restrict__ X,
    const unsigned short* __restrict__ Wq, const unsigned short* __restrict__ Wk,
    const unsigned short* __restrict__ Wv,
    unsigned short* __restrict__ Qo, unsigned short* __restrict__ Ko,
    unsigned short* __restrict__ Vo) {
  __shared__ char lA[4 * 16384];
  __shared__ char lB[4 * 16384];
  int bx, by, bz; swz_block(bx, by, bz);
  const unsigned short* B = (bz == 0) ? Wq : (bz == 1) ? Wk : Wv;
  unsigned short* C = (bz == 0) ? Qo : (bz == 1) ? Ko : Vo;
  gemm_core<unsigned short>(X, B, C, 1024, 2048, 32, by * 256, bx * 256,
                            1.0f, lA, lB);
}

// PV with split-K x2: z=0 writes d_out, z=1 writes partial buffer
__global__ __launch_bounds__(512, 2) void gemm_pv_kernel(
    const unsigned short* __restrict__ S, const unsigned short* __restrict__ Vt,
    float* __restrict__ O, float* __restrict__ P1) {
  __shared__ char lA[4 * 16384];
  __shared__ char lB[4 * 16384];
  int bx, by, bz; swz_block(bx, by, bz);
  const unsigned short* A = S + (size_t)bz * 4096;   // k-offset 4096 elems
  const unsigned short* B = Vt + (size_t)bz * 4096;
  float* C = bz ? P1 : O;
  gemm_core<float>(A, B, C, 1024, 16384, 128, by * 256, bx * 256, 1.0f, lA, lB);
}

__global__ __launch_bounds__(256) void add_kernel(float* __restrict__ out,
                                                  const float* __restrict__ p,
                                                  int n4) {
  int i = blockIdx.x * 256 + threadIdx.x;
  if (i < n4) {
    f32x4 a = ((const f32x4*)out)[i];
    f32x4 b = ((const f32x4*)p)[i];
    ((f32x4*)out)[i] = a + b;
  }
}

// ---- row softmax in place over bf16 S, ncol = 8192 (256 thr x 32 elems) ----
__global__ __launch_bounds__(256) void softmax_kernel(unsigned short* __restrict__ S,
                                                      int ncol) {
  const int t = threadIdx.x;
  unsigned short* rp = S + (size_t)blockIdx.x * ncol;
  ushort8* rv = (ushort8*)rp;
  float f[32];
#pragma unroll
  for (int c = 0; c < 4; ++c) {
    ushort8 v = rv[c * 256 + t];
#pragma unroll
    for (int j = 0; j < 8; ++j) f[c * 8 + j] = bf2f(v[j]);
  }
  float m = -1e30f;
#pragma unroll
  for (int i = 0; i < 32; ++i) m = fmaxf(m, f[i]);
#pragma unroll
  for (int o = 32; o; o >>= 1) m = fmaxf(m, __shfl_xor(m, o));
  __shared__ float red[8];
  if ((t & 63) == 0) red[t >> 6] = m;
  __syncthreads();
  m = fmaxf(fmaxf(red[0], red[1]), fmaxf(red[2], red[3]));

  float s = 0.0f;
#pragma unroll
  for (int i = 0; i < 32; ++i) {
    f[i] = __expf(f[i] - m);
    s += f[i];
  }
#pragma unroll
  for (int o = 32; o; o >>= 1) s += __shfl_xor(s, o);
  if ((t & 63) == 0) red[4 + (t >> 6)] = s;
  __syncthreads();
  s = red[4] + red[5] + red[6] + red[7];
  float inv = 1.0f / s;
#pragma unroll
  for (int c = 0; c < 4; ++c) {
    ushort8 v;
#pragma unroll
    for (int j = 0; j < 8; ++j) v[j] = f2bf(f[c * 8 + j] * inv);
    rv[c * 256 + t] = v;
  }
}

// ---- 64x64 tiled transpose: out[C][R] = in[R][C] (bf16) ----
__global__ __launch_bounds__(256) void transpose_kernel(
    const unsigned short* __restrict__ in, unsigned short* __restrict__ out,
    int R, int Ccols) {
  __shared__ unsigned short tile[64][65];
  const int tx = threadIdx.x & 63, ty = threadIdx.x >> 6;
  const int r0 = blockIdx.y * 64, c0 = blockIdx.x * 64;
#pragma unroll
  for (int i = 0; i < 16; ++i) {
    int r = ty * 16 + i;
    tile[r][tx] = in[(size_t)(r0 + r) * Ccols + c0 + tx];
  }
  __syncthreads();
#pragma unroll
  for (int i = 0; i < 16; ++i) {
    int r = ty * 16 + i;
    out[(size_t)(c0 + r) * R + r0 + tx] = tile[tx][r];
  }
}

extern "C" void kernel_launch(void* const* d_in, const int* in_sizes, int n_in,
                              void* d_out, int out_size, void* d_ws, size_t ws_size,
                              hipStream_t stream) {
  (void)in_sizes; (void)n_in; (void)out_size; (void)ws_size;
  const int N = 8192, D = 1024;
  const float* x  = (const float*)d_in[0];
  const float* Wq = (const float*)d_in[1];
  const float* Wk = (const float*)d_in[2];
  const float* Wv = (const float*)d_in[3];
  float* out = (float*)d_out;

  char* ws = (char*)d_ws;
  size_t off = 0;
  auto alloc = [&](size_t bytes) { char* p = ws + off; off += bytes; return p; };
  unsigned short* xh  = (unsigned short*)alloc((size_t)N * D * 2);  // 16.8 MB
  unsigned short* Wqh = (unsigned short*)alloc((size_t)D * D * 2);  // 2 MB
  unsigned short* Wkh = (unsigned short*)alloc((size_t)D * D * 2);
  unsigned short* Wvh = (unsigned short*)alloc((size_t)D * D * 2);
  unsigned short* Qh  = (unsigned short*)alloc((size_t)N * D * 2);  // 16.8 MB
  unsigned short* Kh  = (unsigned short*)alloc((size_t)N * D * 2);
  unsigned short* Vh  = (unsigned short*)alloc((size_t)N * D * 2);
  unsigned short* S   = (unsigned short*)alloc((size_t)N * N * 2);  // 134.2 MB
  unsigned short* Vth = xh;            // xh dead after QKV
  float* Pbuf = (float*)Qh;            // Qh+Kh (33.6 MB) dead after S-GEMM

  // casts
  cast_kernel<<<(N * D / 8) / 256, 256, 0, stream>>>(x, xh, N * D / 8);
  cast_kernel<<<(D * D / 8) / 256, 256, 0, stream>>>(Wq, Wqh, D * D / 8);
  cast_kernel<<<(D * D / 8) / 256, 256, 0, stream>>>(Wk, Wkh, D * D / 8);
  cast_kernel<<<(D * D / 8) / 256, 256, 0, stream>>>(Wv, Wvh, D * D / 8);

  // Q,K,V = x @ W^T  (fused over z)
  gemm_qkv_kernel<<<dim3(4, 32, 3), 512, 0, stream>>>(xh, Wqh, Wkh, Wvh,
                                                      Qh, Kh, Vh);

  // S = Q @ K^T * (1/32)
  gemm_s_kernel<<<dim3(32, 32), 512, 0, stream>>>(Qh, Kh, S);

  // softmax rows (in place)
  softmax_kernel<<<N, 256, 0, stream>>>(S, N);

  // Vt = V^T  [1024,8192]
  transpose_kernel<<<dim3(D / 64, N / 64), 256, 0, stream>>>(Vh, Vth, N, D);

  // out = P @ Vt^T  (split-K x2, full-chip grid)
  gemm_pv_kernel<<<dim3(4, 32, 2), 512, 0, stream>>>(S, Vth, out, Pbuf);

  // out += partial
  add_kernel<<<(N * D / 4) / 256, 256, 0, stream>>>(out, Pbuf, N * D / 4);
}

// Round 4
// 505.600 us; speedup vs baseline: 1.2164x; 1.2164x over previous
//
#include <hip/hip_runtime.h>
#include <hip/hip_bf16.h>
#include <cstdint>
#include <cstddef>

// ---------------------------------------------------------------------------
// SelfAttentionV1: out = softmax((x Wq^T)(x Wk^T)^T / 32) (x Wv^T)
// N=8192, D=1024. Round 4: ONE barrier per K-tile (was 4). Tile body:
// {8 ds_read + 2 glds -> 16 MFMA -> 4 ds_read + 2 glds -> 16 MFMA ->
//  vmcnt(4) -> barrier}. Ring-4 LDS, distance-2 prefetch (r2 ledger).
// ---------------------------------------------------------------------------

typedef __attribute__((ext_vector_type(8))) short short8;     // bf16x8 MFMA frag
typedef __attribute__((ext_vector_type(8))) unsigned short ushort8;
typedef __attribute__((ext_vector_type(4))) float f32x4;

#define FENCE asm volatile("" ::: "memory")

__device__ __forceinline__ unsigned short f2bf(float f) {
  unsigned u = __float_as_uint(f);
  u += 0x7fffu + ((u >> 16) & 1u);      // round-to-nearest-even
  return (unsigned short)(u >> 16);
}
__device__ __forceinline__ float bf2f(unsigned short h) {
  return __uint_as_float(((unsigned)h) << 16);
}

// async global->LDS, 16 bytes per lane (wave-uniform LDS base + lane*16)
__device__ __forceinline__ void glds16(const void* g, void* l) {
  __builtin_amdgcn_global_load_lds((__attribute__((address_space(1))) void*)g,
                                   (__attribute__((address_space(3))) void*)l,
                                   16, 0, 0);
}

// ---- fp32 -> bf16 cast, 8 elems/thread ----
__global__ __launch_bounds__(256) void cast_kernel(const float* __restrict__ in,
                                                   unsigned short* __restrict__ out,
                                                   int n8) {
  int i = blockIdx.x * 256 + threadIdx.x;
  if (i >= n8) return;
  const f32x4* in4 = (const f32x4*)in;
  f32x4 a = in4[2 * i];
  f32x4 b = in4[2 * i + 1];
  ushort8 o;
#pragma unroll
  for (int j = 0; j < 4; ++j) o[j] = f2bf(a[j]);
#pragma unroll
  for (int j = 0; j < 4; ++j) o[4 + j] = f2bf(b[j]);
  ((ushort8*)out)[i] = o;
}

// ---------------------------------------------------------------------------
// GEMM core: C[gm0..+256, gn0..+256] = scale * A * B^T  (A,B bf16 [*, K] rows)
// 512 thr = 8 waves (2M x 4N), wave-out 128x64 (8x4 frags of 16x16x32).
// BK=32, RING=4 LDS slots (128 KiB), prefetch distance 2, ONE barrier/tile,
// vmcnt(4) boundary (tile t+2's 4 loads stay in flight). Requires NT >= 2.
// LDS plane [256 rows][32 cols] bf16 (64B rows), swizzle: colbyte ^=
// ((row>>1)&3)<<4; staging pre-swizzles the GLOBAL source (rule #21).
// Correctness: reads hit slot t&3 (ready since boundary barrier of t-1);
// glds writes slot (t+2)&3 (not read until 2 boundaries later) -> no
// intra-tile sync needed. Boundary asm has "memory" clobber: no hoisting.
// ---------------------------------------------------------------------------
#define MFMA_OP(mi, ni, av, bv) \
  acc[mi][ni] = __builtin_amdgcn_mfma_f32_16x16x32_bf16(av, bv, acc[mi][ni], 0, 0, 0)

template <typename OutT>
__device__ __forceinline__ void gemm_core(
    const unsigned short* __restrict__ A, const unsigned short* __restrict__ B,
    OutT* __restrict__ C, int ldc, size_t ldab /*row bytes*/, int NT,
    int gm0, int gn0, float scale, char* lA, char* lB) {
  const int tid = threadIdx.x;
  const int lane = tid & 63, w = tid >> 6;
  const int wm = w >> 2, wn = w & 3;            // 2M x 4N wave grid

  // ---- staging (writer) per-lane constants ----
  const int rc0 = w * 32 + (lane >> 2);
  const int rc1 = rc0 + 16;
  const int scol = ((lane & 3) << 4) ^ (((lane >> 3) & 3) << 4);
  const char* pA0 = (const char*)A + (size_t)(gm0 + rc0) * ldab + scol;
  const char* pA1 = (const char*)A + (size_t)(gm0 + rc1) * ldab + scol;
  const char* pB0 = (const char*)B + (size_t)(gn0 + rc0) * ldab + scol;
  const char* pB1 = (const char*)B + (size_t)(gn0 + rc1) * ldab + scol;
  char* dA = lA + w * 2048;   // + slot*16384 (+1024 for second 16 rows)
  char* dB = lB + w * 2048;

  // ---- reader per-lane constants ----
  const int colb = ((lane >> 4) << 4) ^ (((lane >> 1) & 3) << 4);
  const int aoff = (wm * 128 + (lane & 15)) * 64 + colb;
  const int boff = (wn * 64 + (lane & 15)) * 64 + colb;

  f32x4 acc[8][4];
#pragma unroll
  for (int m = 0; m < 8; ++m)
#pragma unroll
    for (int n = 0; n < 4; ++n) acc[m][n] = (f32x4)(0.0f);

  // ---- prologue: stage tiles 0,1; vmcnt(4) => tile 0 landed; barrier.
  for (int t = 0; t < 2; ++t) {
    glds16(pA0 + (size_t)t * 64, dA + t * 16384);
    glds16(pA1 + (size_t)t * 64, dA + t * 16384 + 1024);
    glds16(pB0 + (size_t)t * 64, dB + t * 16384);
    glds16(pB1 + (size_t)t * 64, dB + t * 16384 + 1024);
  }
  asm volatile("s_waitcnt vmcnt(4)" ::: "memory");
  __builtin_amdgcn_s_barrier();
  FENCE;

  // running staging pointers (tile t+2)
  const char* sA0 = pA0 + 128;
  const char* sA1 = pA1 + 128;
  const char* sB0 = pB0 + 128;
  const char* sB1 = pB1 + 128;

#pragma unroll 4
  for (int t = 0; t < NT; ++t) {
    const int slot = t & 3;
    const char* As = lA + slot * 16384;
    const char* Bs = lB + slot * 16384;
    const bool stg = (t + 2 < NT);
    const int s2 = (t + 2) & 3;
    short8 a0, a1, a2, a3, b0, b1, b2, b3;

    // stage A-halves of tile t+2 early (latency ~2 tiles)
    if (stg) {
      glds16(sA0, dA + s2 * 16384);
      glds16(sA1, dA + s2 * 16384 + 1024);
    }
    // reads for first half (A rows mi0-3) + all B
    a0 = *(const short8*)(As + aoff);
    a1 = *(const short8*)(As + aoff + 1024);
    a2 = *(const short8*)(As + aoff + 2048);
    a3 = *(const short8*)(As + aoff + 3072);
    b0 = *(const short8*)(Bs + boff);
    b1 = *(const short8*)(Bs + boff + 1024);
    b2 = *(const short8*)(Bs + boff + 2048);
    b3 = *(const short8*)(Bs + boff + 3072);
    __builtin_amdgcn_s_setprio(1);
    MFMA_OP(0, 0, a0, b0); MFMA_OP(0, 1, a0, b1);
    MFMA_OP(0, 2, a0, b2); MFMA_OP(0, 3, a0, b3);
    MFMA_OP(1, 0, a1, b0); MFMA_OP(1, 1, a1, b1);
    MFMA_OP(1, 2, a1, b2); MFMA_OP(1, 3, a1, b3);
    MFMA_OP(2, 0, a2, b0); MFMA_OP(2, 1, a2, b1);
    MFMA_OP(2, 2, a2, b2); MFMA_OP(2, 3, a2, b3);
    MFMA_OP(3, 0, a3, b0); MFMA_OP(3, 1, a3, b1);
    MFMA_OP(3, 2, a3, b2); MFMA_OP(3, 3, a3, b3);
    __builtin_amdgcn_s_setprio(0);

    // stage B-halves of tile t+2; advance staging pointers
    if (stg) {
      glds16(sB0, dB + s2 * 16384);
      glds16(sB1, dB + s2 * 16384 + 1024);
    }
    sA0 += 64; sA1 += 64; sB0 += 64; sB1 += 64;

    // second half (A rows mi4-7), reuse b0-b3
    a0 = *(const short8*)(As + aoff + 4096);
    a1 = *(const short8*)(As + aoff + 5120);
    a2 = *(const short8*)(As + aoff + 6144);
    a3 = *(const short8*)(As + aoff + 7168);
    __builtin_amdgcn_s_setprio(1);
    MFMA_OP(4, 0, a0, b0); MFMA_OP(4, 1, a0, b1);
    MFMA_OP(4, 2, a0, b2); MFMA_OP(4, 3, a0, b3);
    MFMA_OP(5, 0, a1, b0); MFMA_OP(5, 1, a1, b1);
    MFMA_OP(5, 2, a1, b2); MFMA_OP(5, 3, a1, b3);
    MFMA_OP(6, 0, a2, b0); MFMA_OP(6, 1, a2, b1);
    MFMA_OP(6, 2, a2, b2); MFMA_OP(6, 3, a2, b3);
    MFMA_OP(7, 0, a3, b0); MFMA_OP(7, 1, a3, b1);
    MFMA_OP(7, 2, a3, b2); MFMA_OP(7, 3, a3, b3);
    __builtin_amdgcn_s_setprio(0);

    // boundary: ensure tile t+1 landed; keep tile t+2's 4 loads in flight
    if (stg) asm volatile("s_waitcnt vmcnt(4)" ::: "memory");
    else     asm volatile("s_waitcnt vmcnt(0)" ::: "memory");
    __builtin_amdgcn_s_barrier();
    FENCE;
  }

  // ---- epilogue: C row=(lane>>4)*4+j, col=lane&15 (m89-verified layout)
  const int r0 = gm0 + wm * 128 + ((lane >> 4) << 2);
  const int c0 = gn0 + wn * 64 + (lane & 15);
#pragma unroll
  for (int mi = 0; mi < 8; ++mi) {
#pragma unroll
    for (int ni = 0; ni < 4; ++ni) {
      f32x4 v = acc[mi][ni];
#pragma unroll
      for (int j = 0; j < 4; ++j) {
        float val = v[j] * scale;
        size_t idx = (size_t)(r0 + mi * 16 + j) * ldc + (c0 + ni * 16);
        if (sizeof(OutT) == 2) ((unsigned short*)C)[idx] = f2bf(val);
        else                   ((float*)C)[idx] = val;
      }
    }
  }
}

// bijective XCD chunking: consecutive logical blocks land on the same XCD
__device__ __forceinline__ void swz_block(int& bx, int& by, int& bz) {
  const int gx = gridDim.x, gy = gridDim.y;
  const int f = (blockIdx.z * gy + blockIdx.y) * gx + blockIdx.x;
  const int nwg = gx * gy * gridDim.z;      // all grids are multiples of 8
  const int q = nwg >> 3;
  const int l = (f & 7) * q + (f >> 3);
  bx = l % gx;
  const int r = l / gx;
  by = r % gy;
  bz = r / gy;
}

__global__ __launch_bounds__(512, 2) void gemm_s_kernel(
    const unsigned short* __restrict__ Q, const unsigned short* __restrict__ Kh,
    unsigned short* __restrict__ S) {
  __shared__ char lA[4 * 16384];
  __shared__ char lB[4 * 16384];
  int bx, by, bz; swz_block(bx, by, bz);
  gemm_core<unsigned short>(Q, Kh, S, 8192, 2048, 32, by * 256, bx * 256,
                            0.03125f, lA, lB);
}

__global__ __launch_bounds__(512, 2) void gemm_qkv_kernel(
    const unsigned short* __restrict__ X,
    const unsigned short* __restrict__ Wq, const unsigned short* __restrict__ Wk,
    const unsigned short* __restrict__ Wv,
    unsigned short* __restrict__ Qo, unsigned short* __restrict__ Ko,
    unsigned short* __restrict__ Vo) {
  __shared__ char lA[4 * 16384];
  __shared__ char lB[4 * 16384];
  int bx, by, bz; swz_block(bx, by, bz);
  const unsigned short* B = (bz == 0) ? Wq : (bz == 1) ? Wk : Wv;
  unsigned short* C = (bz == 0) ? Qo : (bz == 1) ? Ko : Vo;
  gemm_core<unsigned short>(X, B, C, 1024, 2048, 32, by * 256, bx * 256,
                            1.0f, lA, lB);
}

// PV with split-K x2: z=0 writes d_out, z=1 writes partial buffer
__global__ __launch_bounds__(512, 2) void gemm_pv_kernel(
    const unsigned short* __restrict__ S, const unsigned short* __restrict__ Vt,
    float* __restrict__ O, float* __restrict__ P1) {
  __shared__ char lA[4 * 16384];
  __shared__ char lB[4 * 16384];
  int bx, by, bz; swz_block(bx, by, bz);
  const unsigned short* A = S + (size_t)bz * 4096;   // k-offset 4096 elems
  const unsigned short* B = Vt + (size_t)bz * 4096;
  float* C = bz ? P1 : O;
  gemm_core<float>(A, B, C, 1024, 16384, 128, by * 256, bx * 256, 1.0f, lA, lB);
}

__global__ __launch_bounds__(256) void add_kernel(float* __restrict__ out,
                                                  const float* __restrict__ p,
                                                  int n4) {
  int i = blockIdx.x * 256 + threadIdx.x;
  if (i < n4) {
    f32x4 a = ((const f32x4*)out)[i];
    f32x4 b = ((const f32x4*)p)[i];
    ((f32x4*)out)[i] = a + b;
  }
}

// ---- row softmax in place over bf16 S, ncol = 8192 (256 thr x 32 elems) ----
__global__ __launch_bounds__(256) void softmax_kernel(unsigned short* __restrict__ S,
                                                      int ncol) {
  const int t = threadIdx.x;
  unsigned short* rp = S + (size_t)blockIdx.x * ncol;
  ushort8* rv = (ushort8*)rp;
  float f[32];
#pragma unroll
  for (int c = 0; c < 4; ++c) {
    ushort8 v = rv[c * 256 + t];
#pragma unroll
    for (int j = 0; j < 8; ++j) f[c * 8 + j] = bf2f(v[j]);
  }
  float m = -1e30f;
#pragma unroll
  for (int i = 0; i < 32; ++i) m = fmaxf(m, f[i]);
#pragma unroll
  for (int o = 32; o; o >>= 1) m = fmaxf(m, __shfl_xor(m, o));
  __shared__ float red[8];
  if ((t & 63) == 0) red[t >> 6] = m;
  __syncthreads();
  m = fmaxf(fmaxf(red[0], red[1]), fmaxf(red[2], red[3]));

  float s = 0.0f;
#pragma unroll
  for (int i = 0; i < 32; ++i) {
    f[i] = __expf(f[i] - m);
    s += f[i];
  }
#pragma unroll
  for (int o = 32; o; o >>= 1) s += __shfl_xor(s, o);
  if ((t & 63) == 0) red[4 + (t >> 6)] = s;
  __syncthreads();
  s = red[4] + red[5] + red[6] + red[7];
  float inv = 1.0f / s;
#pragma unroll
  for (int c = 0; c < 4; ++c) {
    ushort8 v;
#pragma unroll
    for (int j = 0; j < 8; ++j) v[j] = f2bf(f[c * 8 + j] * inv);
    rv[c * 256 + t] = v;
  }
}

// ---- 64x64 tiled transpose: out[C][R] = in[R][C] (bf16) ----
__global__ __launch_bounds__(256) void transpose_kernel(
    const unsigned short* __restrict__ in, unsigned short* __restrict__ out,
    int R, int Ccols) {
  __shared__ unsigned short tile[64][65];
  const int tx = threadIdx.x & 63, ty = threadIdx.x >> 6;
  const int r0 = blockIdx.y * 64, c0 = blockIdx.x * 64;
#pragma unroll
  for (int i = 0; i < 16; ++i) {
    int r = ty * 16 + i;
    tile[r][tx] = in[(size_t)(r0 + r) * Ccols + c0 + tx];
  }
  __syncthreads();
#pragma unroll
  for (int i = 0; i < 16; ++i) {
    int r = ty * 16 + i;
    out[(size_t)(c0 + r) * R + r0 + tx] = tile[tx][r];
  }
}

extern "C" void kernel_launch(void* const* d_in, const int* in_sizes, int n_in,
                              void* d_out, int out_size, void* d_ws, size_t ws_size,
                              hipStream_t stream) {
  (void)in_sizes; (void)n_in; (void)out_size; (void)ws_size;
  const int N = 8192, D = 1024;
  const float* x  = (const float*)d_in[0];
  const float* Wq = (const float*)d_in[1];
  const float* Wk = (const float*)d_in[2];
  const float* Wv = (const float*)d_in[3];
  float* out = (float*)d_out;

  char* ws = (char*)d_ws;
  size_t off = 0;
  auto alloc = [&](size_t bytes) { char* p = ws + off; off += bytes; return p; };
  unsigned short* xh  = (unsigned short*)alloc((size_t)N * D * 2);  // 16.8 MB
  unsigned short* Wqh = (unsigned short*)alloc((size_t)D * D * 2);  // 2 MB
  unsigned short* Wkh = (unsigned short*)alloc((size_t)D * D * 2);
  unsigned short* Wvh = (unsigned short*)alloc((size_t)D * D * 2);
  unsigned short* Qh  = (unsigned short*)alloc((size_t)N * D * 2);  // 16.8 MB
  unsigned short* Kh  = (unsigned short*)alloc((size_t)N * D * 2);
  unsigned short* Vh  = (unsigned short*)alloc((size_t)N * D * 2);
  unsigned short* S   = (unsigned short*)alloc((size_t)N * N * 2);  // 134.2 MB
  unsigned short* Vth = xh;            // xh dead after QKV
  float* Pbuf = (float*)Qh;            // Qh+Kh (33.6 MB) dead after S-GEMM

  // casts
  cast_kernel<<<(N * D / 8) / 256, 256, 0, stream>>>(x, xh, N * D / 8);
  cast_kernel<<<(D * D / 8) / 256, 256, 0, stream>>>(Wq, Wqh, D * D / 8);
  cast_kernel<<<(D * D / 8) / 256, 256, 0, stream>>>(Wk, Wkh, D * D / 8);
  cast_kernel<<<(D * D / 8) / 256, 256, 0, stream>>>(Wv, Wvh, D * D / 8);

  // Q,K,V = x @ W^T  (fused over z)
  gemm_qkv_kernel<<<dim3(4, 32, 3), 512, 0, stream>>>(xh, Wqh, Wkh, Wvh,
                                                      Qh, Kh, Vh);

  // S = Q @ K^T * (1/32)
  gemm_s_kernel<<<dim3(32, 32), 512, 0, stream>>>(Qh, Kh, S);

  // softmax rows (in place)
  softmax_kernel<<<N, 256, 0, stream>>>(S, N);

  // Vt = V^T  [1024,8192]
  transpose_kernel<<<dim3(D / 64, N / 64), 256, 0, stream>>>(Vh, Vth, N, D);

  // out = P @ Vt^T  (split-K x2, full-chip grid)
  gemm_pv_kernel<<<dim3(4, 32, 2), 512, 0, stream>>>(S, Vth, out, Pbuf);

  // out += partial
  add_kernel<<<(N * D / 4) / 256, 256, 0, stream>>>(out, Pbuf, N * D / 4);
}